// Round 8
// baseline (131.281 us; speedup 1.0000x reference)
//
#include <hip/hip_runtime.h>
#include <hip/hip_bf16.h>
#include <stdint.h>

namespace {

constexpr int T_LEN = 2048;
constexpr int NROWS = 192;       // 3*64 rows per head
constexpr int QBLK  = 64;
constexpr int NBH   = 32;        // 2 batches * 16 heads
constexpr int HEAD_ELEMS = T_LEN * 64;       // 131072 bf16 per head per tensor

typedef float f32x4 __attribute__((ext_vector_type(4)));
typedef short bf16x8 __attribute__((ext_vector_type(8)));
typedef short bf16x4 __attribute__((ext_vector_type(4)));

__device__ __forceinline__ unsigned short f2bf(float f) {
  union { float f; unsigned u; } v; v.f = f;
  unsigned r = v.u + 0x7fffu + ((v.u >> 16) & 1u);   // RNE
  return (unsigned short)(r >> 16);
}
__device__ __forceinline__ unsigned pack2(float a, float b) {
  return (unsigned)f2bf(a) | ((unsigned)f2bf(b) << 16);
}
__device__ __forceinline__ float fast_exp2(float x) {
#if __has_builtin(__builtin_amdgcn_exp2f)
  return __builtin_amdgcn_exp2f(x);
#else
  return exp2f(x);
#endif
}
__device__ __forceinline__ f32x4 mfma_16x16x16_bf16(bf16x4 a, bf16x4 b, f32x4 c) {
#if __has_builtin(__builtin_amdgcn_mfma_f32_16x16x16bf16_1k)
  return __builtin_amdgcn_mfma_f32_16x16x16bf16_1k(a, b, c, 0, 0, 0);
#else
  asm("v_mfma_f32_16x16x16_bf16 %0, %1, %2, %0" : "+v"(c) : "v"(a), "v"(b));
  return c;
#endif
}

} // namespace

// Normalize mask to uint8. Stride detect via guaranteed-true mask[0][1] (t=1 < T/2).
__global__ void nm_kernel(const unsigned char* __restrict__ raw,
                          unsigned char* __restrict__ outm, int n) {
  int stride = (raw[1] != 0) ? 1 : ((raw[4] != 0) ? 4 : 8);
  int i = blockIdx.x * blockDim.x + threadIdx.x;
  if (i < n) outm[i] = (raw[(size_t)i * stride] != 0) ? 1 : 0;
}

// ---------------- prepass: fp32 -> bf16 in MFMA-FRAGMENT order ---------------------
// Q: [bh][t][64c] linear (R3 layout), scaled by 0.125*log2(e).
// K: [bh][sb][st][plane][lane][8]  (plane 0: c=8g..8g+7, plane 1: c=32+8g..; lane=g*16+l15,
//    holding row s=sb*64+st*16+l15) — a wave's kf0/kf1 are coalesced 1 KB streams.
__global__ __launch_bounds__(256) void tq8_kernel(const float* __restrict__ qkv,
                                                  short* __restrict__ qtg,
                                                  short* __restrict__ ktg) {
  __shared__ float tile[64][65];
  const int t = threadIdx.x;
  const int which = blockIdx.z;            // 0=Q, 1=K
  const int bh = blockIdx.y;
  const int bx = blockIdx.x;               // 64-wide t/s block (= sb for K)
  const int s0 = bx * 64;
  const float* src = qkv + (size_t)bh * NROWS * T_LEN + (size_t)which * 64 * T_LEN;
  const int c = t >> 2;
  #pragma unroll
  for (int p = 0; p < 4; ++p) {
    int col = (t & 3) * 4 + p * 16;
    float4 v = *(const float4*)&src[(size_t)c * T_LEN + s0 + col];
    tile[c][col] = v.x; tile[c][col + 1] = v.y;
    tile[c][col + 2] = v.z; tile[c][col + 3] = v.w;
  }
  __syncthreads();
  const float scale = which ? 1.0f : 0.18033688011112042f;  // 0.125*log2(e)
  const int s = t & 63;
  #pragma unroll
  for (int p = 0; p < 2; ++p) {
    int jc = (t >> 6) * 2 + p;                    // c-chunk 0..7 (c = jc*8..jc*8+7)
    bf16x8 o;
    #pragma unroll
    for (int i = 0; i < 8; ++i) o[i] = (short)f2bf(tile[jc * 8 + i][s] * scale);
    short* d;
    if (which) {
      const int st = s >> 4, l15 = s & 15;
      const int plane = jc >> 2, g = jc & 3;
      d = ktg + (size_t)bh * HEAD_ELEMS + bx * 4096 + st * 1024 + plane * 512
            + (g * 16 + l15) * 8;
    } else {
      d = qtg + (size_t)bh * HEAD_ELEMS + (size_t)(s0 + s) * 64 + jc * 8;
    }
    *(bf16x8*)d = o;
  }
}

// V: [bh][sb][st][cb][lane][4] (lane=g*16+l15c holds V[c=cb*16+l15c][s=sb*64+st*16+g*4+r])
//    — a wave's per-(st,cb) vf load is a coalesced 512 B stream.
__global__ __launch_bounds__(256) void cv8_kernel(const float* __restrict__ qkv,
                                                  short* __restrict__ vtg) {
  int cid = blockIdx.x * 256 + threadIdx.x;   // (bh, c, cg)
  int bh = cid >> 14;
  int rem = cid & 16383;
  int c = rem >> 8;
  int cg = rem & 255;                          // 8-elem chunk along s
  int grp = cg >> 3, jin = cg & 7;             // sb, 8-chunk within sb
  const float* src = qkv + (size_t)bh * NROWS * T_LEN + (size_t)(128 + c) * T_LEN + cg * 8;
  float4 a = *(const float4*)src;
  float4 b = *(const float4*)(src + 4);
  bf16x4 o0, o1;
  o0[0] = (short)f2bf(a.x); o0[1] = (short)f2bf(a.y);
  o0[2] = (short)f2bf(a.z); o0[3] = (short)f2bf(a.w);
  o1[0] = (short)f2bf(b.x); o1[1] = (short)f2bf(b.y);
  o1[2] = (short)f2bf(b.z); o1[3] = (short)f2bf(b.w);
  const int cb = c >> 4, l15c = c & 15;
  const int st = jin >> 1, g0 = (jin & 1) * 2;
  short* base = vtg + (size_t)bh * HEAD_ELEMS + grp * 4096 + st * 1024 + cb * 256;
  *(bf16x4*)(base + (g0 * 16 + l15c) * 4)       = o0;
  *(bf16x4*)(base + ((g0 + 1) * 16 + l15c) * 4) = o1;
}

// ------ attn8: NO in-loop LDS, NO in-loop barriers. R5 math verbatim; K/V fragments
// read directly from L2-resident fragment-ordered global arrays (coalesced).

__global__ __launch_bounds__(256) void attn8_kernel(const short* __restrict__ qtg,
                                                    const short* __restrict__ ktg,
                                                    const short* __restrict__ vtg,
                                                    const unsigned char* __restrict__ maskn,
                                                    float* __restrict__ out) {
  __shared__ __align__(8) unsigned char Ms[T_LEN];   // 2 KB mask row only

  const int tid  = threadIdx.x;
  const int lane = tid & 63;
  const int wv   = tid >> 6;    // t-window
  const int l15  = lane & 15;
  const int g    = lane >> 4;

  int id = blockIdx.x;
  id = (id & 7) * 128 + (id >> 3);   // bijective XCD swizzle: 4 heads per XCD L2
  const int bh = id >> 5;
  const int t0 = (id & 31) * QBLK;
  const int nb = bh >> 4;

  // stage mask row (2048 B) once
  ((uint2*)Ms)[tid] = ((const uint2*)(maskn + (size_t)nb * T_LEN))[tid];

  // Q fragments straight from global (linear [t][c] rows)
  const int t_lane = t0 + wv * 16 + l15;
  const short* Qrow = qtg + (size_t)bh * HEAD_ELEMS + (size_t)t_lane * 64;
  const bf16x8 qf0 = *(const bf16x8*)(Qrow + g * 8);
  const bf16x8 qf1 = *(const bf16x8*)(Qrow + 32 + g * 8);
  __syncthreads();                     // Ms visible (only barrier before epilogue)
  const bool invt = (Ms[t_lane] == 0); // masked row -> uniform softmax

  f32x4 acc[4];
  #pragma unroll
  for (int i = 0; i < 4; ++i) acc[i] = (f32x4){0.f, 0.f, 0.f, 0.f};
  float l_part = 0.0f;

  // per-lane fragment base pointers
  const short* __restrict__ Kf = ktg + (size_t)bh * HEAD_ELEMS + lane * 8;
  const short* __restrict__ Vf = vtg + (size_t)bh * HEAD_ELEMS + lane * 4;

  for (int sb = 0; sb < T_LEN / 64; ++sb) {
    const short* kb = Kf + sb * 4096;
    const short* vb = Vf + sb * 4096;
    const int s0 = sb * 64;
    #pragma unroll
    for (int st = 0; st < 4; ++st) {
      bf16x8 kf0 = *(const bf16x8*)(kb + st * 1024);
      bf16x8 kf1 = *(const bf16x8*)(kb + st * 1024 + 512);
      f32x4 S = (f32x4){0.f, 0.f, 0.f, 0.f};
      S = __builtin_amdgcn_mfma_f32_16x16x32_bf16(kf0, qf0, S, 0, 0, 0);
      S = __builtin_amdgcn_mfma_f32_16x16x32_bf16(kf1, qf1, S, 0, 0, 0);

      // lane holds S[s = s0+st*16+g*4+r][t = t_lane], already in log2 domain
      const unsigned m4 = *(const unsigned*)&Ms[s0 + st * 16 + g * 4];
      float p0, p1, p2, p3;
      {
        float x0 = ((m4 & 0x000000ffu) ? S[0] : -1.0e30f);
        float x1 = ((m4 & 0x0000ff00u) ? S[1] : -1.0e30f);
        float x2 = ((m4 & 0x00ff0000u) ? S[2] : -1.0e30f);
        float x3 = ((m4 & 0xff000000u) ? S[3] : -1.0e30f);
        p0 = fast_exp2(invt ? 0.0f : x0);
        p1 = fast_exp2(invt ? 0.0f : x1);
        p2 = fast_exp2(invt ? 0.0f : x2);
        p3 = fast_exp2(invt ? 0.0f : x3);
      }
      l_part += (p0 + p1) + (p2 + p3);

      union { bf16x4 v; __hip_bfloat162 h[2]; } pf;
      pf.h[0] = __float22bfloat162_rn(float2{p0, p1});
      pf.h[1] = __float22bfloat162_rn(float2{p2, p3});

      #pragma unroll
      for (int cb = 0; cb < 4; ++cb) {
        bf16x4 vf = *(const bf16x4*)(vb + st * 1024 + cb * 256);
        acc[cb] = mfma_16x16x16_bf16(vf, pf.v, acc[cb]);
      }
    }
  }

  // epilogue: single l reduction (plain sum without max-tracking)
  l_part += __shfl_xor(l_part, 16, 64);
  l_part += __shfl_xor(l_part, 32, 64);
  const float il = 1.0f / l_part;
  const size_t out_base = (size_t)bh * 64 * T_LEN;
  #pragma unroll
  for (int cb = 0; cb < 4; ++cb) {
    #pragma unroll
    for (int r = 0; r < 4; ++r) {
      int c = cb * 16 + g * 4 + r;
      out[out_base + (size_t)c * T_LEN + t_lane] = acc[cb][r] * il;
    }
  }
}

// ---------------- fallback path (round-1 kernel, used if ws too small) ------------

__global__ __launch_bounds__(256) void attn_fb_kernel(const float* __restrict__ qkv,
                                                      const unsigned char* __restrict__ maskn,
                                                      float* __restrict__ out) {
  __shared__ __align__(16) short Kt[QBLK * 72];
  __shared__ __align__(16) short Vs[64 * 72];
  __shared__ __align__(16) unsigned char Ms[T_LEN];

  const int tid  = threadIdx.x;
  const int lane = tid & 63;
  const int wv   = tid >> 6;
  const int l15  = lane & 15;
  const int g    = lane >> 4;

  const int bh = blockIdx.y;
  const int nb = bh >> 4;
  const int t0 = blockIdx.x * QBLK;

  const float* __restrict__ Qg = qkv + (size_t)bh * NROWS * T_LEN;
  const float* __restrict__ Kg = Qg + (size_t)64 * T_LEN;
  const float* __restrict__ Vg = Qg + (size_t)128 * T_LEN;

  {
    const uint2* src = (const uint2*)(maskn + (size_t)nb * T_LEN);
    ((uint2*)Ms)[tid] = src[tid];
  }
  {
    const int c2 = (tid >> 6) * 2;
    const int s  = tid & 63;
    #pragma unroll
    for (int p = 0; p < 8; ++p) {
      int c = p * 8 + c2;
      float f0 = Qg[(size_t)c * T_LEN + t0 + s] * 0.125f;
      float f1 = Qg[(size_t)(c + 1) * T_LEN + t0 + s] * 0.125f;
      *(unsigned*)&Kt[s * 72 + c] = pack2(f0, f1);
    }
  }
  __syncthreads();

  bf16x8 qf0 = *(const bf16x8*)&Kt[(wv * 16 + l15) * 72 + g * 8];
  bf16x8 qf1 = *(const bf16x8*)&Kt[(wv * 16 + l15) * 72 + 32 + g * 8];
  const int t_lane = t0 + wv * 16 + l15;
  const bool invt = (Ms[t_lane] == 0);

  f32x4 acc[4];
  #pragma unroll
  for (int i = 0; i < 4; ++i) acc[i] = (f32x4){0.f, 0.f, 0.f, 0.f};
  float m_run = -3.0e38f;
  float l_run = 0.0f;

  for (int sb = 0; sb < T_LEN / 64; ++sb) {
    const int s0 = sb * 64;
    __syncthreads();
    {
      const int c2 = (tid >> 6) * 2;
      const int s  = tid & 63;
      #pragma unroll
      for (int p = 0; p < 8; ++p) {
        int c = p * 8 + c2;
        float f0 = Kg[(size_t)c * T_LEN + s0 + s];
        float f1 = Kg[(size_t)(c + 1) * T_LEN + s0 + s];
        *(unsigned*)&Kt[s * 72 + c] = pack2(f0, f1);
      }
    }
    {
      const int cv = (tid >> 5);
      const int s2 = tid & 31;
      #pragma unroll
      for (int p = 0; p < 8; ++p) {
        int c = p * 8 + cv;
        float2 f = *(const float2*)&Vg[(size_t)c * T_LEN + s0 + 2 * s2];
        *(unsigned*)&Vs[c * 72 + 2 * s2] = pack2(f.x, f.y);
      }
    }
    __syncthreads();

    #pragma unroll
    for (int st = 0; st < 4; ++st) {
      const int srow = st * 16 + l15;
      bf16x8 kf0 = *(const bf16x8*)&Kt[srow * 72 + g * 8];
      bf16x8 kf1 = *(const bf16x8*)&Kt[srow * 72 + 32 + g * 8];
      f32x4 S = (f32x4){0.f, 0.f, 0.f, 0.f};
      S = __builtin_amdgcn_mfma_f32_16x16x32_bf16(kf0, qf0, S, 0, 0, 0);
      S = __builtin_amdgcn_mfma_f32_16x16x32_bf16(kf1, qf1, S, 0, 0, 0);

      const unsigned m4 = *(const unsigned*)&Ms[s0 + st * 16 + g * 4];
      float vals[4];
      #pragma unroll
      for (int r = 0; r < 4; ++r) {
        float x = ((m4 >> (8 * r)) & 0xffu) ? S[r] : -1.0e30f;
        vals[r] = invt ? 0.0f : x;
      }
      float pm = fmaxf(fmaxf(vals[0], vals[1]), fmaxf(vals[2], vals[3]));
      pm = fmaxf(pm, __shfl_xor(pm, 16, 64));
      pm = fmaxf(pm, __shfl_xor(pm, 32, 64));
      const float newm = fmaxf(m_run, pm);
      const float alpha = fast_exp2((m_run - newm) * 1.44269504f);
      float p0 = fast_exp2((vals[0] - newm) * 1.44269504f);
      float p1 = fast_exp2((vals[1] - newm) * 1.44269504f);
      float p2 = fast_exp2((vals[2] - newm) * 1.44269504f);
      float p3 = fast_exp2((vals[3] - newm) * 1.44269504f);
      float ps = (p0 + p1) + (p2 + p3);
      ps += __shfl_xor(ps, 16, 64);
      ps += __shfl_xor(ps, 32, 64);
      l_run = l_run * alpha + ps;
      m_run = newm;
      if (__any(alpha < 1.0f)) {
        #pragma unroll
        for (int cb = 0; cb < 4; ++cb)
          #pragma unroll
          for (int r = 0; r < 4; ++r) acc[cb][r] *= alpha;
      }
      bf16x4 pf;
      pf[0] = (short)f2bf(p0); pf[1] = (short)f2bf(p1);
      pf[2] = (short)f2bf(p2); pf[3] = (short)f2bf(p3);
      #pragma unroll
      for (int cb = 0; cb < 4; ++cb) {
        bf16x4 vf = *(const bf16x4*)&Vs[(cb * 16 + l15) * 72 + st * 16 + g * 4];
        acc[cb] = mfma_16x16x16_bf16(vf, pf, acc[cb]);
      }
    }
  }

  const float il = 1.0f / l_run;
  const size_t out_base = (size_t)bh * 64 * T_LEN;
  #pragma unroll
  for (int cb = 0; cb < 4; ++cb) {
    #pragma unroll
    for (int r = 0; r < 4; ++r) {
      int c = cb * 16 + g * 4 + r;
      out[out_base + (size_t)c * T_LEN + t_lane] = acc[cb][r] * il;
    }
  }
}

// ---------------- launch ----------------

extern "C" void kernel_launch(void* const* d_in, const int* in_sizes, int n_in,
                              void* d_out, int out_size, void* d_ws, size_t ws_size,
                              hipStream_t stream) {
  (void)n_in; (void)out_size;
  const float* qkv = (const float*)d_in[0];
  const unsigned char* mraw = (const unsigned char*)d_in[1];
  float* out = (float*)d_out;
  const int mask_elems = in_sizes[1];   // 2*2048

  // ws layout: qtg(8 MB) | ktg frags(8 MB) | vtg frags(8 MB) | maskn(4 KB)
  const size_t SZ = (size_t)NBH * HEAD_ELEMS * sizeof(short);   // 8388608
  const size_t need = 3 * SZ + (size_t)mask_elems;
  if (ws_size >= need) {
    short* qtg = (short*)d_ws;
    short* ktg = (short*)((char*)d_ws + SZ);
    short* vtg = (short*)((char*)d_ws + 2 * SZ);
    unsigned char* maskn = (unsigned char*)d_ws + 3 * SZ;
    nm_kernel<<<(mask_elems + 255) / 256, 256, 0, stream>>>(mraw, maskn, mask_elems);
    tq8_kernel<<<dim3(T_LEN / 64, NBH, 2), 256, 0, stream>>>(qkv, qtg, ktg);
    cv8_kernel<<<(NBH * 64 * 256) / 256, 256, 0, stream>>>(qkv, vtg);
    attn8_kernel<<<dim3(NBH * 32), 256, 0, stream>>>(qtg, ktg, vtg, maskn, out);
  } else {
    unsigned char* maskn = (unsigned char*)d_ws;
    nm_kernel<<<(mask_elems + 255) / 256, 256, 0, stream>>>(mraw, maskn, mask_elems);
    attn_fb_kernel<<<dim3(T_LEN / QBLK, NBH), 256, 0, stream>>>(qkv, maskn, out);
  }
}

// Round 9
// 91.372 us; speedup vs baseline: 1.4368x; 1.4368x over previous
//
#include <hip/hip_runtime.h>
#include <hip/hip_bf16.h>
#include <stdint.h>

namespace {

constexpr int T_LEN = 2048;
constexpr int NROWS = 192;       // 3*64 rows per head
constexpr int QBLK  = 64;
constexpr int NBH   = 32;        // 2 batches * 16 heads
constexpr int KT_STRIDE = 72;    // padded row stride (bf16 elems) — R1/R3-validated
constexpr int TILE_ELEMS = 64 * KT_STRIDE;   // 4608 elems = 9216 B per 64-tile
constexpr int TILE_BYTES = TILE_ELEMS * 2;   // 9216 B

typedef float f32x4 __attribute__((ext_vector_type(4)));
typedef short bf16x8 __attribute__((ext_vector_type(8)));
typedef short bf16x4 __attribute__((ext_vector_type(4)));

__device__ __forceinline__ unsigned short f2bf(float f) {
  union { float f; unsigned u; } v; v.f = f;
  unsigned r = v.u + 0x7fffu + ((v.u >> 16) & 1u);   // RNE
  return (unsigned short)(r >> 16);
}
__device__ __forceinline__ unsigned pack2(float a, float b) {
  return (unsigned)f2bf(a) | ((unsigned)f2bf(b) << 16);
}
__device__ __forceinline__ float fast_exp2(float x) {
#if __has_builtin(__builtin_amdgcn_exp2f)
  return __builtin_amdgcn_exp2f(x);
#else
  return exp2f(x);
#endif
}
__device__ __forceinline__ f32x4 mfma_16x16x16_bf16(bf16x4 a, bf16x4 b, f32x4 c) {
#if __has_builtin(__builtin_amdgcn_mfma_f32_16x16x16bf16_1k)
  return __builtin_amdgcn_mfma_f32_16x16x16bf16_1k(a, b, c, 0, 0, 0);
#else
  asm("v_mfma_f32_16x16x16_bf16 %0, %1, %2, %0" : "+v"(c) : "v"(a), "v"(b));
  return c;
#endif
}
// Async global->LDS DMA, 16B per lane: LDS dest = wave-uniform base + lane*16.
__device__ __forceinline__ void gload_lds16(const void* g, void* l) {
  __builtin_amdgcn_global_load_lds(
      (const __attribute__((address_space(1))) unsigned int*)g,
      (__attribute__((address_space(3))) unsigned int*)l, 16, 0, 0);
}

} // namespace

// Normalize mask to uint8 (fallback path). Stride detect via guaranteed-true mask[0][1].
__global__ void nm_kernel(const unsigned char* __restrict__ raw,
                          unsigned char* __restrict__ outm, int n) {
  int stride = (raw[1] != 0) ? 1 : ((raw[4] != 0) ? 4 : 8);
  int i = blockIdx.x * blockDim.x + threadIdx.x;
  if (i < n) outm[i] = (raw[(size_t)i * stride] != 0) ? 1 : 0;
}

// mask -> fp32 additive bias rows {0,-1e30}, plus one all-zero row at offset n.
__global__ void bias9_kernel(const unsigned char* __restrict__ raw,
                             float* __restrict__ bias, int n) {
  int stride = (raw[1] != 0) ? 1 : ((raw[4] != 0) ? 4 : 8);
  int i = blockIdx.x * blockDim.x + threadIdx.x;
  if (i < n) bias[i] = (raw[(size_t)i * stride] != 0) ? 0.0f : -1.0e30f;
  else if (i < n + T_LEN) bias[i] = 0.0f;
}

// ---------------- prepass: fp32 -> bf16, R1-validated LDS image --------------------

// Q: [bh][t][64c] linear, scaled by 0.125*log2(e); masked-t rows fully zeroed.
// K: [bh][sb][64s][72] padded tiles, unscaled.
__global__ __launch_bounds__(256) void tq9_kernel(const float* __restrict__ qkv,
                                                  const unsigned char* __restrict__ mraw,
                                                  short* __restrict__ qtg,
                                                  short* __restrict__ ktg) {
  __shared__ float tile[64][65];
  const int t = threadIdx.x;
  const int which = blockIdx.z;            // 0=Q, 1=K
  const int bh = blockIdx.y;
  const int bx = blockIdx.x;               // 64-wide t/s block
  const int s0 = bx * 64;
  const float* src = qkv + (size_t)bh * NROWS * T_LEN + (size_t)which * 64 * T_LEN;
  const int c = t >> 2;
  #pragma unroll
  for (int p = 0; p < 4; ++p) {
    int col = (t & 3) * 4 + p * 16;
    float4 v = *(const float4*)&src[(size_t)c * T_LEN + s0 + col];
    tile[c][col] = v.x; tile[c][col + 1] = v.y;
    tile[c][col + 2] = v.z; tile[c][col + 3] = v.w;
  }
  __syncthreads();
  const int s = t & 63;
  float scale;
  if (which) {
    scale = 1.0f;
  } else {
    const int mstride = (mraw[1] != 0) ? 1 : ((mraw[4] != 0) ? 4 : 8);
    const int nb = bh >> 4;
    const bool live = mraw[((size_t)nb * T_LEN + s0 + s) * mstride] != 0;
    scale = live ? 0.18033688011112042f : 0.0f;   // 0.125*log2(e), 0 for masked t
  }
  #pragma unroll
  for (int p = 0; p < 2; ++p) {
    int jc = (t >> 6) * 2 + p;                    // c-chunk 0..7
    bf16x4 o0, o1;
    #pragma unroll
    for (int i = 0; i < 4; ++i) {
      o0[i] = (short)f2bf(tile[jc * 8 + i][s] * scale);
      o1[i] = (short)f2bf(tile[jc * 8 + 4 + i][s] * scale);
    }
    short* d = which
      ? (ktg + (size_t)(bh * 32 + bx) * TILE_ELEMS + s * KT_STRIDE + jc * 8)
      : (qtg + (size_t)bh * T_LEN * 64 + (size_t)(s0 + s) * 64 + jc * 8);
    *(bf16x4*)d = o0;
    *(bf16x4*)(d + 4) = o1;
  }
}

// V: [bh][sb][64c][72] padded tiles (row c = 64 s-values + pad), unscaled.
__global__ __launch_bounds__(256) void cv3_kernel(const float* __restrict__ qkv,
                                                  short* __restrict__ vtg) {
  int cid = blockIdx.x * 256 + threadIdx.x;   // (bh, c, cg)
  int bh = cid >> 14;
  int rem = cid & 16383;
  int c = rem >> 8;
  int cg = rem & 255;                          // 8-elem chunk along s
  int grp = cg >> 3, jin = cg & 7;             // tile index, chunk within tile
  const float* src = qkv + (size_t)bh * NROWS * T_LEN + (size_t)(128 + c) * T_LEN + cg * 8;
  float4 a = *(const float4*)src;
  float4 b = *(const float4*)(src + 4);
  bf16x4 o0, o1;
  o0[0] = (short)f2bf(a.x); o0[1] = (short)f2bf(a.y);
  o0[2] = (short)f2bf(a.z); o0[3] = (short)f2bf(a.w);
  o1[0] = (short)f2bf(b.x); o1[1] = (short)f2bf(b.y);
  o1[2] = (short)f2bf(b.z); o1[3] = (short)f2bf(b.w);
  short* d = vtg + (size_t)(bh * 32 + grp) * TILE_ELEMS + c * KT_STRIDE + jin * 8;
  *(bf16x4*)d = o0;
  *(bf16x4*)(d + 4) = o1;
}

// ------ attn9: R6 structure (8 waves, split-s, LDS dbuf, 1 barrier/iter) with
// (1) global_load_lds DMA staging (no staging VALU / ds_writes / prefetch regs),
// (2) additive-bias masking (4 adds replace 16 selects; no Ms; zero-row for masked t).

__global__ __launch_bounds__(512) void attn9_kernel(const short* __restrict__ qtg,
                                                    const short* __restrict__ ktg,
                                                    const short* __restrict__ vtg,
                                                    const float* __restrict__ bias,
                                                    int mask_elems,
                                                    float* __restrict__ out) {
  __shared__ __align__(16) short Kt[2][TILE_ELEMS];   // [64s][72] double-buffered
  __shared__ __align__(16) short Vs[2][TILE_ELEMS];   // [64c][72] double-buffered

  const int tid  = threadIdx.x;
  const int lane = tid & 63;
  const int wv   = tid >> 6;    // 0..7
  const int tw   = wv & 3;      // t-window within block
  const int sh   = wv >> 2;     // s-half: 0 -> st 0,1 ; 1 -> st 2,3
  const int l15  = lane & 15;
  const int g    = lane >> 4;

  int id = blockIdx.x;
  id = (id & 7) * 128 + (id >> 3);   // bijective XCD swizzle (bit-rotation)
  const int bh = id >> 5;
  const int t0 = (id & 31) * QBLK;
  const int nb = bh >> 4;

  // Q fragments straight from global (linear [t][c] rows; masked-t rows are zeroed)
  const int t_lane = t0 + tw * 16 + l15;
  const short* Qrow = qtg + (size_t)bh * T_LEN * 64 + (size_t)t_lane * 64;
  const bf16x8 qf0 = *(const bf16x8*)(Qrow + g * 8);
  const bf16x8 qf1 = *(const bf16x8*)(Qrow + 32 + g * 8);

  // per-lane bias row: live t -> batch row; masked t -> zero row (uniform softmax)
  const float bt = bias[(size_t)nb * T_LEN + t_lane];
  const float* __restrict__ brow = bias + ((bt != 0.0f) ? (size_t)mask_elems
                                                        : (size_t)nb * T_LEN);

  const char* __restrict__ kt0 = (const char*)(ktg + (size_t)bh * 32 * TILE_ELEMS);
  const char* __restrict__ vt0 = (const char*)(vtg + (size_t)bh * 32 * TILE_ELEMS);

  // prologue: DMA tile 0 -> buf 0 (9216 B each = 8 full wave-chunks + 1 extra)
  gload_lds16(kt0 + wv * 1024 + lane * 16, (char*)Kt[0] + wv * 1024);
  gload_lds16(vt0 + wv * 1024 + lane * 16, (char*)Vs[0] + wv * 1024);
  if (wv == 0) gload_lds16(kt0 + 8192 + lane * 16, (char*)Kt[0] + 8192);
  if (wv == 1) gload_lds16(vt0 + 8192 + lane * 16, (char*)Vs[0] + 8192);
  __syncthreads();                     // drains DMA (vmcnt) + joins waves

  f32x4 acc[4];
  #pragma unroll
  for (int i = 0; i < 4; ++i) acc[i] = (f32x4){0.f, 0.f, 0.f, 0.f};
  float l_part = 0.0f;

  int cur = 0;
  for (int sb = 0; sb < T_LEN / 64; ++sb) {
    // issue next tile's DMA first: flies under this tile's compute (T14)
    if (sb + 1 < T_LEN / 64) {
      const char* ks = kt0 + (size_t)(sb + 1) * TILE_BYTES;
      const char* vs = vt0 + (size_t)(sb + 1) * TILE_BYTES;
      char* Ktn = (char*)Kt[cur ^ 1];
      char* Vsn = (char*)Vs[cur ^ 1];
      gload_lds16(ks + wv * 1024 + lane * 16, Ktn + wv * 1024);
      gload_lds16(vs + wv * 1024 + lane * 16, Vsn + wv * 1024);
      if (wv == 0) gload_lds16(ks + 8192 + lane * 16, Ktn + 8192);
      if (wv == 1) gload_lds16(vs + 8192 + lane * 16, Vsn + 8192);
    }

    const short* Ktc = Kt[cur];
    const short* Vsc = Vs[cur];
    const int s0 = sb * 64;
    #pragma unroll
    for (int sti = 0; sti < 2; ++sti) {
      const int st = sh * 2 + sti;
      const int srow = st * 16 + l15;
      bf16x8 kf0 = *(const bf16x8*)&Ktc[srow * KT_STRIDE + g * 8];
      bf16x8 kf1 = *(const bf16x8*)&Ktc[srow * KT_STRIDE + 32 + g * 8];
      f32x4 S = (f32x4){0.f, 0.f, 0.f, 0.f};
      S = __builtin_amdgcn_mfma_f32_16x16x32_bf16(kf0, qf0, S, 0, 0, 0);
      S = __builtin_amdgcn_mfma_f32_16x16x32_bf16(kf1, qf1, S, 0, 0, 0);

      // lane holds S[s = s0+st*16+g*4+r][t = t_lane], already in log2 domain.
      // masking: additive bias (0 / -1e30); masked-t lanes read the zero row.
      const f32x4 b4 = *(const f32x4*)&brow[s0 + st * 16 + g * 4];
      float p0 = fast_exp2(S[0] + b4[0]);
      float p1 = fast_exp2(S[1] + b4[1]);
      float p2 = fast_exp2(S[2] + b4[2]);
      float p3 = fast_exp2(S[3] + b4[3]);
      l_part += (p0 + p1) + (p2 + p3);

      union { bf16x4 v; __hip_bfloat162 h[2]; } pf;
      pf.h[0] = __float22bfloat162_rn(float2{p0, p1});
      pf.h[1] = __float22bfloat162_rn(float2{p2, p3});

      #pragma unroll
      for (int cb = 0; cb < 4; ++cb) {
        bf16x4 vf = *(const bf16x4*)&Vsc[(cb * 16 + l15) * KT_STRIDE + st * 16 + g * 4];
        acc[cb] = mfma_16x16x16_bf16(vf, pf.v, acc[cb]);
      }
    }

    __syncthreads();                   // reads of buf[cur] done; DMA into buf[cur^1] drained
    cur ^= 1;
  }

  // ---- cross-wave combine: waves 4-7 dump partials into dead Kt LDS, waves 0-3 add
  // scratch layout: [t within block 0..63][68]: 64 acc floats + 4 l (per g) = 17408 B
  float* scratch = (float*)Kt;
  const int trow = tw * 16 + l15;
  if (wv >= 4) {
    float* row = scratch + trow * 68;
    #pragma unroll
    for (int cb = 0; cb < 4; ++cb) *(f32x4*)&row[cb * 16 + g * 4] = acc[cb];
    row[64 + g] = l_part;
  }
  __syncthreads();
  if (wv < 4) {
    const float* row = scratch + trow * 68;
    #pragma unroll
    for (int cb = 0; cb < 4; ++cb) acc[cb] += *(const f32x4*)&row[cb * 16 + g * 4];
    l_part += row[64 + g];

    l_part += __shfl_xor(l_part, 16, 64);
    l_part += __shfl_xor(l_part, 32, 64);
    const float il = 1.0f / l_part;
    const size_t out_base = (size_t)bh * 64 * T_LEN;
    #pragma unroll
    for (int cb = 0; cb < 4; ++cb) {
      #pragma unroll
      for (int r = 0; r < 4; ++r) {
        int c = cb * 16 + g * 4 + r;
        out[out_base + (size_t)c * T_LEN + t_lane] = acc[cb][r] * il;
      }
    }
  }
}

// ---------------- fallback path (round-1 kernel, used if ws too small) ------------

__global__ __launch_bounds__(256) void attn_fb_kernel(const float* __restrict__ qkv,
                                                      const unsigned char* __restrict__ maskn,
                                                      float* __restrict__ out) {
  __shared__ __align__(16) short Kt[QBLK * KT_STRIDE];
  __shared__ __align__(16) short Vs[64 * KT_STRIDE];
  __shared__ __align__(16) unsigned char Ms[T_LEN];

  const int tid  = threadIdx.x;
  const int lane = tid & 63;
  const int wv   = tid >> 6;
  const int l15  = lane & 15;
  const int g    = lane >> 4;

  const int bh = blockIdx.y;
  const int nb = bh >> 4;
  const int t0 = blockIdx.x * QBLK;

  const float* __restrict__ Qg = qkv + (size_t)bh * NROWS * T_LEN;
  const float* __restrict__ Kg = Qg + (size_t)64 * T_LEN;
  const float* __restrict__ Vg = Qg + (size_t)128 * T_LEN;

  {
    const uint2* src = (const uint2*)(maskn + (size_t)nb * T_LEN);
    ((uint2*)Ms)[tid] = src[tid];
  }
  {
    const int c2 = (tid >> 6) * 2;
    const int s  = tid & 63;
    #pragma unroll
    for (int p = 0; p < 8; ++p) {
      int c = p * 8 + c2;
      float f0 = Qg[(size_t)c * T_LEN + t0 + s] * 0.125f;
      float f1 = Qg[(size_t)(c + 1) * T_LEN + t0 + s] * 0.125f;
      *(unsigned*)&Kt[s * KT_STRIDE + c] = pack2(f0, f1);
    }
  }
  __syncthreads();

  bf16x8 qf0 = *(const bf16x8*)&Kt[(wv * 16 + l15) * KT_STRIDE + g * 8];
  bf16x8 qf1 = *(const bf16x8*)&Kt[(wv * 16 + l15) * KT_STRIDE + 32 + g * 8];
  const int t_lane = t0 + wv * 16 + l15;
  const bool invt = (Ms[t_lane] == 0);

  f32x4 acc[4];
  #pragma unroll
  for (int i = 0; i < 4; ++i) acc[i] = (f32x4){0.f, 0.f, 0.f, 0.f};
  float m_run = -3.0e38f;
  float l_run = 0.0f;

  for (int sb = 0; sb < T_LEN / 64; ++sb) {
    const int s0 = sb * 64;
    __syncthreads();
    {
      const int c2 = (tid >> 6) * 2;
      const int s  = tid & 63;
      #pragma unroll
      for (int p = 0; p < 8; ++p) {
        int c = p * 8 + c2;
        float f0 = Kg[(size_t)c * T_LEN + s0 + s];
        float f1 = Kg[(size_t)(c + 1) * T_LEN + s0 + s];
        *(unsigned*)&Kt[s * KT_STRIDE + c] = pack2(f0, f1);
      }
    }
    {
      const int cv = (tid >> 5);
      const int s2 = tid & 31;
      #pragma unroll
      for (int p = 0; p < 8; ++p) {
        int c = p * 8 + cv;
        float2 f = *(const float2*)&Vg[(size_t)c * T_LEN + s0 + 2 * s2];
        *(unsigned*)&Vs[c * KT_STRIDE + 2 * s2] = pack2(f.x, f.y);
      }
    }
    __syncthreads();

    #pragma unroll
    for (int st = 0; st < 4; ++st) {
      const int srow = st * 16 + l15;
      bf16x8 kf0 = *(const bf16x8*)&Kt[srow * KT_STRIDE + g * 8];
      bf16x8 kf1 = *(const bf16x8*)&Kt[srow * KT_STRIDE + 32 + g * 8];
      f32x4 S = (f32x4){0.f, 0.f, 0.f, 0.f};
      S = __builtin_amdgcn_mfma_f32_16x16x32_bf16(kf0, qf0, S, 0, 0, 0);
      S = __builtin_amdgcn_mfma_f32_16x16x32_bf16(kf1, qf1, S, 0, 0, 0);

      const unsigned m4 = *(const unsigned*)&Ms[s0 + st * 16 + g * 4];
      float vals[4];
      #pragma unroll
      for (int r = 0; r < 4; ++r) {
        float x = ((m4 >> (8 * r)) & 0xffu) ? S[r] : -1.0e30f;
        vals[r] = invt ? 0.0f : x;
      }
      float pm = fmaxf(fmaxf(vals[0], vals[1]), fmaxf(vals[2], vals[3]));
      pm = fmaxf(pm, __shfl_xor(pm, 16, 64));
      pm = fmaxf(pm, __shfl_xor(pm, 32, 64));
      const float newm = fmaxf(m_run, pm);
      const float alpha = fast_exp2((m_run - newm) * 1.44269504f);
      float p0 = fast_exp2((vals[0] - newm) * 1.44269504f);
      float p1 = fast_exp2((vals[1] - newm) * 1.44269504f);
      float p2 = fast_exp2((vals[2] - newm) * 1.44269504f);
      float p3 = fast_exp2((vals[3] - newm) * 1.44269504f);
      float ps = (p0 + p1) + (p2 + p3);
      ps += __shfl_xor(ps, 16, 64);
      ps += __shfl_xor(ps, 32, 64);
      l_run = l_run * alpha + ps;
      m_run = newm;
      if (__any(alpha < 1.0f)) {
        #pragma unroll
        for (int cb = 0; cb < 4; ++cb)
          #pragma unroll
          for (int r = 0; r < 4; ++r) acc[cb][r] *= alpha;
      }
      bf16x4 pf;
      pf[0] = (short)f2bf(p0); pf[1] = (short)f2bf(p1);
      pf[2] = (short)f2bf(p2); pf[3] = (short)f2bf(p3);
      #pragma unroll
      for (int cb = 0; cb < 4; ++cb) {
        bf16x4 vf = *(const bf16x4*)&Vs[(cb * 16 + l15) * KT_STRIDE + st * 16 + g * 4];
        acc[cb] = mfma_16x16x16_bf16(vf, pf, acc[cb]);
      }
    }
  }

  const float il = 1.0f / l_run;
  const size_t out_base = (size_t)bh * 64 * T_LEN;
  #pragma unroll
  for (int cb = 0; cb < 4; ++cb) {
    #pragma unroll
    for (int r = 0; r < 4; ++r) {
      int c = cb * 16 + g * 4 + r;
      out[out_base + (size_t)c * T_LEN + t_lane] = acc[cb][r] * il;
    }
  }
}

// ---------------- launch ----------------

extern "C" void kernel_launch(void* const* d_in, const int* in_sizes, int n_in,
                              void* d_out, int out_size, void* d_ws, size_t ws_size,
                              hipStream_t stream) {
  (void)n_in; (void)out_size;
  const float* qkv = (const float*)d_in[0];
  const unsigned char* mraw = (const unsigned char*)d_in[1];
  float* out = (float*)d_out;
  const int mask_elems = in_sizes[1];   // 2*2048

  // ws layout: qtg(8 MB) | ktg tiles(9 MB) | vtg tiles(9 MB) | bias((mask_elems+2048)*4)
  const size_t QSZ = (size_t)NBH * T_LEN * 64 * sizeof(short);          // 8388608
  const size_t TSZ = (size_t)NBH * 32 * TILE_ELEMS * sizeof(short);     // 9437184
  const size_t BSZ = (size_t)(mask_elems + T_LEN) * sizeof(float);
  const size_t need = QSZ + 2 * TSZ + BSZ;
  if (ws_size >= need) {
    short* qtg = (short*)d_ws;
    short* ktg = (short*)((char*)d_ws + QSZ);
    short* vtg = (short*)((char*)d_ws + QSZ + TSZ);
    float* bias = (float*)((char*)d_ws + QSZ + 2 * TSZ);
    bias9_kernel<<<(mask_elems + T_LEN + 255) / 256, 256, 0, stream>>>(mraw, bias, mask_elems);
    tq9_kernel<<<dim3(T_LEN / 64, NBH, 2), 256, 0, stream>>>(qkv, mraw, qtg, ktg);
    cv3_kernel<<<(NBH * 64 * 256) / 256, 256, 0, stream>>>(qkv, vtg);
    attn9_kernel<<<dim3(NBH * 32), 512, 0, stream>>>(qtg, ktg, vtg, bias, mask_elems, out);
  } else {
    unsigned char* maskn = (unsigned char*)d_ws;
    nm_kernel<<<(mask_elems + 255) / 256, 256, 0, stream>>>(mraw, maskn, mask_elems);
    attn_fb_kernel<<<dim3(T_LEN / QBLK, NBH), 256, 0, stream>>>(qkv, maskn, out);
  }
}